// Round 13
// baseline (295.805 us; speedup 1.0000x reference)
//
#include <hip/hip_runtime.h>
#include <hip/hip_bf16.h>

#define HW 128
#define HW2 16384
#define NEG 0.2f

typedef __attribute__((ext_vector_type(8))) short short8;
typedef __attribute__((ext_vector_type(4))) float f32x4;
typedef __attribute__((ext_vector_type(2))) float f32x2;
typedef __attribute__((ext_vector_type(16))) float f32x16;

__device__ __forceinline__ float lrelu(float v) { return v >= 0.f ? v : NEG * v; }
__device__ __forceinline__ unsigned short f2bf(float f) {
    unsigned int u = __float_as_uint(f);
    u = (u + 0x7fffu + ((u >> 16) & 1u)) >> 16;
    return (unsigned short)u;
}
__device__ __forceinline__ unsigned int pk2(float a, float b) {
    __hip_bfloat162 h = __float22bfloat162_rn(float2{a, b});
    return *(unsigned int*)&h;
}
__device__ __forceinline__ float2 upk(unsigned int u) {
    return float2{__uint_as_float(u << 16), __uint_as_float(u & 0xffff0000u)};
}
__device__ __forceinline__ f32x2 upkv(unsigned int u) {
    f32x2 r;
    r.x = __uint_as_float(u << 16);
    r.y = __uint_as_float(u & 0xffff0000u);
    return r;
}

// ---------------------------------------------------------------------------
// Weight repack fp32 [M][Cin][3][3] -> bf16 fragment-contiguous layouts.
// mode 0 (16x16x32 fragments): [g][st(3)][mt(M/16)][lane][8]
//   elem = W[mt*16+l15][g*8+cl][tap], tap = st*4+quad (taps>8 zero).
// mode 1 (32x32x16 fragments): [g][ki(5)][mt(M/32)][lane][8]
//   elem = W[mt*32+(lane&31)][g*8+cl][tap], tap = ki*2+(lane>>5) (tap>8 zero).
// ---------------------------------------------------------------------------
struct WSeg { const float* s; unsigned short* d; int K9; int NMT; int validM; int n; int mode; };
struct WArgs { WSeg seg[9]; };

__global__ void wrepack_kernel(WArgs a)
{
    const WSeg sg = a.seg[blockIdx.y];
    int i = blockIdx.x * 256 + threadIdx.x;
    if (i >= sg.n) return;
    int cl = i & 7, lane = (i >> 3) & 63;
    int rest = i >> 9;
    unsigned short v = 0;
    if (sg.mode == 0) {
        int mt = rest % sg.NMT, gs = rest / sg.NMT;
        int st = gs % 3, g = gs / 3;
        int quad = lane >> 4, l15 = lane & 15;
        int co = mt * 16 + l15, tap = st * 4 + quad;
        if (tap < 9 && co < sg.validM)
            v = f2bf(sg.s[(size_t)co * sg.K9 + (g * 8 + cl) * 9 + tap]);
    } else {
        int mt = rest % sg.NMT, kig = rest / sg.NMT;
        int ki = kig % 5, g = kig / 5;
        int hi = lane >> 5, l31 = lane & 31;
        int co = mt * 32 + l31, tap = ki * 2 + hi;
        if (tap < 9 && co < sg.validM)
            v = f2bf(sg.s[(size_t)co * sg.K9 + (g * 8 + cl) * 9 + tap]);
    }
    sg.d[i] = v;
}

// ---------------------------------------------------------------------------
// Fused plain conv (N=64 tile, 2x32), single barrier per group, A-prefetch.
// r13: GEMM = mfma_f32_32x32x16_bf16, K=80 (5 ki; tap9 pad zeroed in weights,
// B-address clamped to tap 8 -> stays inside 4x34 patch).
// NT=2 (Cout=128): wave wv -> m-tile wv, both n-halves (A disjoint).
// NT=1 (Cout=64):  wave wv -> (m = wv>>1, n = wv&1).
// Staging/pipeline = r5 measured-best form (balanced rows, dbuf, 1 bar/grp).
// ---------------------------------------------------------------------------
template <int NMT, int NT, int SRCF>
__global__ __launch_bounds__(256, 4) void fused_conv(
    const void* __restrict__ actv, const unsigned short* __restrict__ wpad,
    const float* __restrict__ bias, unsigned short* __restrict__ outb,
    int Cin, int Cout)
{
    constexpr int PB = 136 * 16;                 // 2176 B per patch buffer
    constexpr int SMB = 64 * 136 * 2;            // Es (17408) > 2*PB
    __shared__ char smem[SMB];
    unsigned short* Es = (unsigned short*)smem;

    const int t = threadIdx.x;
    const int tile = blockIdx.x, b = blockIdx.z;
    const int lane = t & 63, wv = t >> 6;
    const int l31 = lane & 31, hi = lane >> 5;
    const int y0 = (tile >> 2) * 2, x0 = (tile & 3) * 32;
    const int ngrp = Cin >> 3;
    const int NSTR2 = NMT * 512;                 // shorts per (g,ki) slab

    // balanced staging: wave wv -> patch row wv, lanes 0..33 -> cols
    const bool sok = lane < 34;
    const int gy = y0 - 1 + wv, gx = x0 - 1 + lane;
    const bool pok = sok && gy >= 0 && gy < HW && gx >= 0 && gx < HW;
    const int gp = pok ? gy * HW + gx : 0;
    const int slot = wv * 34 + lane;

    const float* actf = (const float*)actv;
    const unsigned short* acth = (const unsigned short*)actv;
    const size_t bofs = (size_t)b * Cin * HW2;

    // B-frag addresses: pixel p = nh*32+l31 (ly=nh, lx=l31), tap=ki*2+hi
    int baddr2[5][NT];
#pragma unroll
    for (int ki = 0; ki < 5; ++ki) {
        int tap = ki * 2 + hi; tap = tap > 8 ? 8 : tap;
        int ky = (tap * 11) >> 5, kx = tap - 3 * ky;
#pragma unroll
        for (int n = 0; n < NT; ++n) {
            int nh = (NT == 2) ? n : (wv & 1);
            baddr2[ki][n] = ((nh + ky) * 34 + l31 + kx) * 16;
        }
    }
    const int mt0 = (NT == 2) ? wv : (wv >> 1);
    const size_t abase2 = (size_t)(mt0 * 512 + lane * 8);

    f32x16 acc2[NT];
#pragma unroll
    for (int n = 0; n < NT; ++n) acc2[n] = (f32x16)(0.f);

    auto load_grp = [&](int g) -> uint4 {
        uint4 u; u.x = u.y = u.z = u.w = 0;
        if (!pok) return u;
        if (SRCF == 1) {
            u = *(const uint4*)(acth + bofs + ((size_t)g * HW2 + gp) * 8);
        } else {
            const float* pl = actf + bofs + (size_t)(g * 8) * HW2 + gp;
            float v0 = pl[0], v1 = pl[HW2], v2 = pl[2 * HW2], v3 = pl[3 * HW2];
            float v4 = pl[4 * HW2], v5 = pl[5 * HW2], v6 = pl[6 * HW2], v7 = pl[7 * HW2];
            u.x = pk2(v0, v1); u.y = pk2(v2, v3);
            u.z = pk2(v4, v5); u.w = pk2(v6, v7);
        }
        return u;
    };

    short8 apre[5];
    auto loadA = [&](int g) {
#pragma unroll
        for (int ki = 0; ki < 5; ++ki)
            apre[ki] = *(const short8*)(
                wpad + (size_t)(g * 5 + ki) * NSTR2 + abase2);
    };

    uint4 cur = load_grp(0);
    if (sok) *(uint4*)(smem + slot * 16) = cur;           // patch buf 0
    loadA(0);
    if (ngrp > 1) cur = load_grp(1);
    __syncthreads();

    for (int g = 0; g < ngrp; ++g) {
        char* pb = smem + (g & 1) * PB;
#pragma unroll
        for (int ki = 0; ki < 5; ++ki) {
            short8 bf[NT];
#pragma unroll
            for (int n = 0; n < NT; ++n)
                bf[n] = *(const short8*)(pb + baddr2[ki][n]);
#pragma unroll
            for (int n = 0; n < NT; ++n)
                acc2[n] = __builtin_amdgcn_mfma_f32_32x32x16_bf16(
                    apre[ki], bf[n], acc2[n], 0, 0, 0);
        }
        if (g + 1 < ngrp) {
            if (sok) *(uint4*)(smem + ((g + 1) & 1) * PB + slot * 16) = cur;
            loadA(g + 1);
            if (g + 2 < ngrp) cur = load_grp(g + 2);
        }
        __syncthreads();
    }

    // epilogue (32x32 C/D: col=lane&31, row=(reg&3)+8*(reg>>2)+4*hi)
    {
        constexpr int ESTR = 136;
        int mtb = mt0 * 32;
#pragma unroll
        for (int n = 0; n < NT; ++n) {
            int px2 = ((NT == 2) ? n : (wv & 1)) * 32 + l31;
#pragma unroll
            for (int q = 0; q < 4; ++q) {
                int co = mtb + q * 8 + hi * 4;
                unsigned int u0 = pk2(lrelu(acc2[n][q * 4 + 0] + bias[co]),
                                      lrelu(acc2[n][q * 4 + 1] + bias[co + 1]));
                unsigned int u1 = pk2(lrelu(acc2[n][q * 4 + 2] + bias[co + 2]),
                                      lrelu(acc2[n][q * 4 + 3] + bias[co + 3]));
                uint2 u; u.x = u0; u.y = u1;
                *(uint2*)&Es[px2 * ESTR + co] = u;
            }
        }
        __syncthreads();
        const int ng8 = Cout >> 3;
        unsigned short* ob = outb + (size_t)b * Cout * HW2;
        for (int tt = t; tt < 64 * ng8; tt += 256) {
            int cg = tt >> 6, px = tt & 63;
            int gp2 = (y0 + (px >> 5)) * HW + x0 + (px & 31);
            *(uint4*)(ob + ((size_t)cg * HW2 + gp2) * 8) =
                *(const uint4*)&Es[px * ESTR + cg * 8];
        }
    }
}

// ---------------------------------------------------------------------------
// Fused deformable conv WITH in-kernel offset prediction (phase A).
// [r12 measured best: 56.0us] Phase A: r5 pipelined 4x34 patch -> offbuf.
// Loop B: 32x32x16 K=80 GEMM, NT=2: wave->m-tile, both n-halves; NT=1:
// wave->(m,n). r5 schedule (patch+Cs dbuf, A-prefetch, 1 barrier/group).
// mode 0: NHWC8 bf16 out + leaky; mode 1: planar fp32 out + leaky.
// ---------------------------------------------------------------------------
template <int NMT, int NT>
__global__ __launch_bounds__(256, 4) void fused_deform(
    const unsigned short* __restrict__ acth,
    const unsigned short* __restrict__ woff, const float* __restrict__ obias,
    const unsigned short* __restrict__ wpad, const float* __restrict__ bias,
    unsigned short* __restrict__ outb, float* __restrict__ outf,
    int Cin, int Cout, int mode)
{
    constexpr int PATW = 43, PATR = 8, PATP = PATR * PATW;  // 344
    constexpr int CSTR = 88;
    constexpr int PB = PATP * 16;                 // 5504 B
    constexpr int CB = 64 * CSTR * 2;             // 11264 B
    constexpr int SMB = 2 * PB + 2 * CB;          // 33536 B
    constexpr int OPB = 136 * 16;                 // 2176 B small patch (phase A)
    __shared__ char smem[SMB];
    unsigned short* Es = (unsigned short*)smem;   // epilogue alias (17408 B)

    const int t = threadIdx.x;
    const int tile = blockIdx.x, b = blockIdx.z;
    const int lane = t & 63, wv = t >> 6, quad = lane >> 4, l15 = lane & 15;
    const int l31 = lane & 31, hi = lane >> 5;
    const int y0 = (tile >> 2) * 2, x0 = (tile & 3) * 32;
    const int ngrp = Cin >> 3;
    const int NSTR2 = NMT * 512;                  // shorts per (g,ki) slab
    const int py0 = y0 - 3, px0 = x0 - 5;
    const size_t bofs = (size_t)b * Cin * HW2;

    // zero Cs k-pad [72,80) in BOTH buffers: 2 bufs x 64 rows x 1 uint4 = 128
    for (int i = t; i < 128; i += 256) {
        int bu = i >> 6, p = i & 63;
        uint4 z; z.x = z.y = z.z = z.w = 0;
        *(uint4*)(smem + 2 * PB + bu * CB + (p * CSTR + 72) * 2) = z;
    }

    // ---- phase A: offset conv (18ch) -> offbuf [64][20] f32 @ [4352,9472) ----
    {
        float* offbuf = (float*)(smem + 2 * OPB);
        const bool asok = lane < 34;
        const int agy = y0 - 1 + wv, agx = x0 - 1 + lane;
        const bool apok = asok && agy >= 0 && agy < HW && agx >= 0 && agx < HW;
        const int agp = apok ? agy * HW + agx : 0;
        const int aslot = wv * 34 + lane;

        const int mtile = wv & 1, npair = wv >> 1;
        int obad[3][2];
#pragma unroll
        for (int st = 0; st < 3; ++st) {
            int tap = st * 4 + quad; tap = tap > 8 ? 8 : tap;
            int ky = (tap * 11) >> 5, kx = tap - 3 * ky;
#pragma unroll
            for (int nn = 0; nn < 2; ++nn) {
                int p = (2 * npair + nn) * 16 + l15, ly = p >> 5, lx = p & 31;
                obad[st][nn] = ((ly + ky) * 34 + lx + kx) * 16;
            }
        }
        const size_t oa0 = (size_t)(mtile * 512 + lane * 8);

        f32x4 oacc[2];
        oacc[0] = (f32x4)(0.f); oacc[1] = (f32x4)(0.f);
        short8 oapre[3];
        auto loadAO = [&](int g) {
#pragma unroll
            for (int st = 0; st < 3; ++st)
                oapre[st] = *(const short8*)(woff + (size_t)(g * 3 + st) * 1024 + oa0);
        };
        auto load_g = [&](int g) -> uint4 {
            uint4 u; u.x = u.y = u.z = u.w = 0;
            if (apok) u = *(const uint4*)(acth + bofs + ((size_t)g * HW2 + agp) * 8);
            return u;
        };

        uint4 cur = load_g(0);
        if (asok) *(uint4*)(smem + aslot * 16) = cur;
        loadAO(0);
        if (ngrp > 1) cur = load_g(1);
        __syncthreads();

        for (int g = 0; g < ngrp; ++g) {
            const char* pb = smem + (g & 1) * OPB;
#pragma unroll
            for (int st = 0; st < 3; ++st) {
                short8 a = oapre[st];
#pragma unroll
                for (int nn = 0; nn < 2; ++nn) {
                    short8 bf = *(const short8*)(pb + obad[st][nn]);
                    oacc[nn] = __builtin_amdgcn_mfma_f32_16x16x32_bf16(
                        a, bf, oacc[nn], 0, 0, 0);
                }
            }
            if (g + 1 < ngrp) {
                if (asok) *(uint4*)(smem + ((g + 1) & 1) * OPB + aslot * 16) = cur;
                loadAO(g + 1);
                if (g + 2 < ngrp) cur = load_g(g + 2);
            }
            __syncthreads();
        }

        {
            int co0 = mtile * 16 + quad * 4;
            if (co0 < 18) {
#pragma unroll
                for (int nn = 0; nn < 2; ++nn) {
                    int px = (2 * npair + nn) * 16 + l15;
#pragma unroll
                    for (int r = 0; r < 4; ++r)
                        if (co0 + r < 18)
                            offbuf[px * 20 + co0 + r] = oacc[nn][r] + obias[co0 + r];
                }
            }
        }
        __syncthreads();
    }
    const float* offbuf = (const float*)(smem + 2 * OPB);

    // ---- phase 0: fast-path tap params (slots t, t+256, t+512) ----
    float w00[3], w01[3], w10[3], w11[3];
    int pbase[3], csad[3], svalid[3];
    int allin = 1;
    {
#pragma unroll
        for (int s = 0; s < 3; ++s) {
            int task = t + s * 256;
            svalid[s] = task < 576;
            int task2 = svalid[s] ? task : 0;
            int p = task2 / 9, k = task2 - 9 * p;
            int yy = y0 + (p >> 5), xx = x0 + (p & 31);
            float2 dd = *(const float2*)(offbuf + p * 20 + 2 * k);
            float dy = dd.x, dx = dd.y;
            float py = (float)(yy + k / 3 - 1) + dy;
            float px = (float)(xx + k % 3 - 1) + dx;
            float fy = floorf(py), fx = floorf(px);
            float wy = py - fy, wx = px - fx;
            int iy = (int)fy, ix = (int)fx;
            w00[s] = (1.f - wy) * (1.f - wx);
            w01[s] = (1.f - wy) * wx;
            w10[s] = wy * (1.f - wx);
            w11[s] = wy * wx;
            pbase[s] = ((iy - py0) * PATW + (ix - px0)) * 16;   // bytes
            csad[s] = (p * CSTR + k * 8) * 2;                   // bytes
            bool ip = iy >= py0 && iy + 1 <= py0 + (PATR - 1)
                   && ix >= px0 && ix + 1 <= px0 + (PATW - 1);
            if (!ip) allin = 0;
        }
    }
    const int fast = __syncthreads_and(allin);

    // balanced staging: wave wv owns slots [wv*86, wv*86+86)
    const int s0 = wv * 86 + lane;                 // always < 344
    const int r0 = s0 / PATW, c0_ = s0 - PATW * r0;
    const int gy0_ = py0 + r0, gx0_ = px0 + c0_;
    const bool ok0 = gy0_ >= 0 && gy0_ < HW && gx0_ >= 0 && gx0_ < HW;
    const int go0 = ok0 ? gy0_ * HW + gx0_ : 0;
    const bool has1 = lane < 22;
    const int s1 = wv * 86 + 64 + lane;            // < 344 when has1
    const int r1 = s1 / PATW, c1_ = s1 - PATW * r1;
    const int gy1_ = py0 + r1, gx1_ = px0 + c1_;
    const bool ok1 = has1 && gy1_ >= 0 && gy1_ < HW && gx1_ >= 0 && gx1_ < HW;
    const int go1 = ok1 ? gy1_ * HW + gx1_ : 0;

    // 32x32x16 tiling: NT=2 -> m-tile = wv, n in {0,1}; NT=1 -> (wv>>1, wv&1)
    const int mt0 = (NT == 2) ? wv : (wv >> 1);
    const size_t abase2 = (size_t)(mt0 * 512 + lane * 8);
    int bbn[NT];
#pragma unroll
    for (int n = 0; n < NT; ++n) {
        int nh = (NT == 2) ? n : (wv & 1);
        bbn[n] = (nh * 32 + l31) * (CSTR * 2) + hi * 16;
    }

    f32x16 acc2[NT];
#pragma unroll
    for (int n = 0; n < NT; ++n) acc2[n] = (f32x16)(0.f);

    short8 apre[5];
    auto loadA = [&](int g) {
#pragma unroll
        for (int ki = 0; ki < 5; ++ki)
            apre[ki] = *(const short8*)(
                wpad + (size_t)(g * 5 + ki) * NSTR2 + abase2);
    };

    auto mfma32 = [&](const char* cs) {
#pragma unroll
        for (int ki = 0; ki < 5; ++ki) {
            short8 bf[NT];
#pragma unroll
            for (int n = 0; n < NT; ++n)
                bf[n] = *(const short8*)(cs + bbn[n] + ki * 32);
#pragma unroll
            for (int n = 0; n < NT; ++n)
                acc2[n] = __builtin_amdgcn_mfma_f32_32x32x16_bf16(
                    apre[ki], bf[n], acc2[n], 0, 0, 0);
        }
    };

    if (fast) {
        uint4 u0, u1;
        u0.x = u0.y = u0.z = u0.w = 0; u1 = u0;
        if (ok0) u0 = *(const uint4*)(acth + bofs + (size_t)go0 * 8);
        if (ok1) u1 = *(const uint4*)(acth + bofs + (size_t)go1 * 8);
        *(uint4*)(smem + s0 * 16) = u0;
        if (has1) *(uint4*)(smem + s1 * 16) = u1;
        if (ngrp > 1) {
            u0.x = u0.y = u0.z = u0.w = 0; u1 = u0;
            if (ok0) u0 = *(const uint4*)(acth + bofs + ((size_t)HW2 + go0) * 8);
            if (ok1) u1 = *(const uint4*)(acth + bofs + ((size_t)HW2 + go1) * 8);
        }
        __syncthreads();

        for (int g = 0; g < ngrp; ++g) {
            const char* pb = smem + (g & 1) * PB;
            char* csW = smem + 2 * PB + (g & 1) * CB;

            // (a) MFMA for previous group (A already in regs)
            if (g > 0)
                mfma32(smem + 2 * PB + ((g - 1) & 1) * CB);

            // (b) col build g -> Cs[g&1] (packed f32x2 math)
#pragma unroll
            for (int s = 0; s < 3; ++s) {
                if (!svalid[s]) continue;
                const char* base = pb + pbase[s];
                uint4 c00 = *(const uint4*)base;
                uint4 c01 = *(const uint4*)(base + 16);
                uint4 c10 = *(const uint4*)(base + PATW * 16);
                uint4 c11 = *(const uint4*)(base + PATW * 16 + 16);
                f32x2 vw0 = (f32x2)(w00[s]), vw1 = (f32x2)(w01[s]);
                f32x2 vw2 = (f32x2)(w10[s]), vw3 = (f32x2)(w11[s]);
                f32x2 a0 = vw0 * upkv(c00.x) + vw1 * upkv(c01.x)
                         + vw2 * upkv(c10.x) + vw3 * upkv(c11.x);
                f32x2 a1 = vw0 * upkv(c00.y) + vw1 * upkv(c01.y)
                         + vw2 * upkv(c10.y) + vw3 * upkv(c11.y);
                f32x2 a2 = vw0 * upkv(c00.z) + vw1 * upkv(c01.z)
                         + vw2 * upkv(c10.z) + vw3 * upkv(c11.z);
                f32x2 a3 = vw0 * upkv(c00.w) + vw1 * upkv(c01.w)
                         + vw2 * upkv(c10.w) + vw3 * upkv(c11.w);
                uint4 ou;
                ou.x = pk2(a0.x, a0.y); ou.y = pk2(a1.x, a1.y);
                ou.z = pk2(a2.x, a2.y); ou.w = pk2(a3.x, a3.y);
                *(uint4*)(csW + csad[s]) = ou;
            }

            // (c) write patch g+1; (d) prefetch A(g); (e) load act g+2
            if (g + 1 < ngrp) {
                char* pn = smem + ((g + 1) & 1) * PB;
                *(uint4*)(pn + s0 * 16) = u0;
                if (has1) *(uint4*)(pn + s1 * 16) = u1;
            }
            loadA(g);
            if (g + 2 < ngrp) {
                u0.x = u0.y = u0.z = u0.w = 0; u1 = u0;
                if (ok0) u0 = *(const uint4*)(acth + bofs +
                                              ((size_t)(g + 2) * HW2 + go0) * 8);
                if (ok1) u1 = *(const uint4*)(acth + bofs +
                                              ((size_t)(g + 2) * HW2 + go1) * 8);
            }
            __syncthreads();
        }
        // final group's MFMA (apre = A(ngrp-1))
        mfma32(smem + 2 * PB + ((ngrp - 1) & 1) * CB);
    } else {
        // slow path (rare): recompute taps per group from offbuf; global
        // corner reads; 2 barriers per group; single Cs buffer (buffer 0).
        char* csW = smem + 2 * PB;
        for (int g = 0; g < ngrp; ++g) {
            const unsigned short* gb = acth + bofs + (size_t)g * HW2 * 8;
#pragma unroll
            for (int s = 0; s < 3; ++s) {
                if (!svalid[s]) continue;
                int task = t + s * 256;
                int p = task / 9, k = task - 9 * p;
                int yy = y0 + (p >> 5), xx = x0 + (p & 31);
                float2 dd = *(const float2*)(offbuf + p * 20 + 2 * k);
                float dy = dd.x, dx = dd.y;
                float py = (float)(yy + k / 3 - 1) + dy;
                float px = (float)(xx + k % 3 - 1) + dx;
                float fy = floorf(py), fx = floorf(px);
                float wy = py - fy, wx = px - fx;
                int iy = (int)fy, ix = (int)fx;
                float f0 = 0, f1 = 0, f2 = 0, f3 = 0, f4 = 0, f5 = 0, f6 = 0, f7 = 0;
#pragma unroll
                for (int q = 0; q < 4; ++q) {
                    int ddy = q >> 1, ddx = q & 1;
                    int sy = iy + ddy, sx = ix + ddx;
                    float w = (ddy ? wy : 1.f - wy) * (ddx ? wx : 1.f - wx);
                    if (sy < 0 || sy >= HW || sx < 0 || sx >= HW) w = 0.f;
                    int cy = min(max(sy, 0), HW - 1), cx = min(max(sx, 0), HW - 1);
                    uint4 c = *(const uint4*)(gb + (size_t)(cy * HW + cx) * 8);
                    float2 p0 = upk(c.x), p1 = upk(c.y), p2 = upk(c.z), p3 = upk(c.w);
                    f0 += w * p0.x; f1 += w * p0.y; f2 += w * p1.x; f3 += w * p1.y;
                    f4 += w * p2.x; f5 += w * p2.y; f6 += w * p3.x; f7 += w * p3.y;
                }
                uint4 ou;
                ou.x = pk2(f0, f1); ou.y = pk2(f2, f3);
                ou.z = pk2(f4, f5); ou.w = pk2(f6, f7);
                *(uint4*)(csW + csad[s]) = ou;
            }
            __syncthreads();
            loadA(g);
            mfma32(csW);
            __syncthreads();
        }
    }

    // ---- epilogue (32x32 C/D layout: col=lane&31,
    //      row = (reg&3) + 8*(reg>>2) + 4*(lane>>5)) ----
    __syncthreads();   // Es aliases patch/Cs regions
    if (mode == 0) {
        constexpr int ESTR = 136;
        int mtb = mt0 * 32;
#pragma unroll
        for (int n = 0; n < NT; ++n) {
            int px2 = ((NT == 2) ? n : (wv & 1)) * 32 + l31;
#pragma unroll
            for (int q = 0; q < 4; ++q) {
                int co = mtb + q * 8 + hi * 4;
                unsigned int u0 = pk2(lrelu(acc2[n][q * 4 + 0] + bias[co]),
                                      lrelu(acc2[n][q * 4 + 1] + bias[co + 1]));
                unsigned int u1 = pk2(lrelu(acc2[n][q * 4 + 2] + bias[co + 2]),
                                      lrelu(acc2[n][q * 4 + 3] + bias[co + 3]));
                uint2 u; u.x = u0; u.y = u1;
                *(uint2*)&Es[px2 * ESTR + co] = u;
            }
        }
        __syncthreads();
        const int ng8 = Cout >> 3;
        unsigned short* ob = outb + (size_t)b * Cout * HW2;
        for (int tt = t; tt < 64 * ng8; tt += 256) {
            int cg = tt >> 6, px = tt & 63;
            int gp2 = (y0 + (px >> 5)) * HW + x0 + (px & 31);
            *(uint4*)(ob + ((size_t)cg * HW2 + gp2) * 8) =
                *(const uint4*)&Es[px * ESTR + cg * 8];
        }
    } else {
        float* of = outf + (size_t)b * Cout * HW2;
        int mtb = mt0 * 32;
#pragma unroll
        for (int n = 0; n < NT; ++n) {
            int px2 = ((NT == 2) ? n : (wv & 1)) * 32 + l31;
            int gp2 = (y0 + (px2 >> 5)) * HW + x0 + (px2 & 31);
#pragma unroll
            for (int q = 0; q < 4; ++q) {
                int co = mtb + q * 8 + hi * 4;
#pragma unroll
                for (int rr = 0; rr < 4; ++rr)
                    of[(size_t)(co + rr) * HW2 + gp2] =
                        lrelu(acc2[n][q * 4 + rr] + bias[co + rr]);
            }
        }
    }
}

// ---------------------------------------------------------------------------
extern "C" void kernel_launch(void* const* d_in, const int* in_sizes, int n_in,
                              void* d_out, int out_size, void* d_ws,
                              size_t ws_size, hipStream_t stream)
{
    const float* x = (const float*)d_in[0];
    const float* p[18];
    for (int i = 0; i < 18; ++i) p[i] = (const float*)d_in[1 + i];

    char* ws = (char*)d_ws;
    unsigned short* A1 = (unsigned short*)ws;              // NHWC8 bf16
    unsigned short* A2 = (unsigned short*)(ws + 16777216);
    unsigned short* WB = (unsigned short*)(ws + 38273024);

    unsigned short* Wc1 = WB;             // mode1: 8g x5 x4mt x512  (81920)
    unsigned short* Wo1 = Wc1 + 81920;    // mode0: 16g x3 x2mt x512 (49152)
    unsigned short* Wd1 = Wo1 + 49152;    // mode1: 16g x5 x4mt x512 (163840)
    unsigned short* Wc2 = Wd1 + 163840;   // mode1: 16g x5 x4mt x512 (163840)
    unsigned short* Wo2 = Wc2 + 163840;   // mode0: 16g x3 x2mt x512 (49152)
    unsigned short* Wd2 = Wo2 + 49152;    // mode1: 16g x5 x4mt x512 (163840)
    unsigned short* Wc3 = Wd2 + 163840;   // mode1: 16g x5 x2mt x512 (81920)
    unsigned short* Wo3 = Wc3 + 81920;    // mode0: 8g x3 x2mt x512  (24576)
    unsigned short* Wd3 = Wo3 + 24576;    // mode1: 8g x5 x2mt x512  (40960)

    WArgs wa;
    wa.seg[0] = {p[0],  Wc1,  576, 4, 128,  81920, 1};
    wa.seg[1] = {p[2],  Wo1, 1152, 2,  18,  49152, 0};
    wa.seg[2] = {p[4],  Wd1, 1152, 4, 128, 163840, 1};
    wa.seg[3] = {p[6],  Wc2, 1152, 4, 128, 163840, 1};
    wa.seg[4] = {p[8],  Wo2, 1152, 2,  18,  49152, 0};
    wa.seg[5] = {p[10], Wd2, 1152, 4, 128, 163840, 1};
    wa.seg[6] = {p[12], Wc3, 1152, 2,  64,  81920, 1};
    wa.seg[7] = {p[14], Wo3,  576, 2,  18,  24576, 0};
    wa.seg[8] = {p[16], Wd3,  576, 2,  64,  40960, 1};
    wrepack_kernel<<<dim3(768, 9), 256, 0, stream>>>(wa);

    dim3 g(256, 1, 4);      // 2x32 tiles
    // stage 1: conv (fp32 planar in, staged) -> deform(fused offset conv)
    fused_conv<4, 2, 0><<<g, 256, 0, stream>>>(x, Wc1, p[1], A1, 64, 128);
    fused_deform<4, 2><<<g, 256, 0, stream>>>(A1, Wo1, p[3], Wd1, p[5], A2, nullptr, 128, 128, 0);
    // stage 2
    fused_conv<4, 2, 1><<<g, 256, 0, stream>>>(A2, Wc2, p[7], A1, 128, 128);
    fused_deform<4, 2><<<g, 256, 0, stream>>>(A1, Wo2, p[9], Wd2, p[11], A2, nullptr, 128, 128, 0);
    // stage 3
    fused_conv<2, 1, 1><<<g, 256, 0, stream>>>(A2, Wc3, p[13], A1, 128, 64);
    fused_deform<2, 1><<<g, 256, 0, stream>>>(A1, Wo3, p[15], Wd3, p[17], nullptr, (float*)d_out, 64, 64, 1);
}

// Round 14
// 286.763 us; speedup vs baseline: 1.0315x; 1.0315x over previous
//
#include <hip/hip_runtime.h>
#include <hip/hip_bf16.h>

#define HW 128
#define HW2 16384
#define NEG 0.2f

typedef __attribute__((ext_vector_type(8))) short short8;
typedef __attribute__((ext_vector_type(4))) float f32x4;
typedef __attribute__((ext_vector_type(2))) float f32x2;
typedef __attribute__((ext_vector_type(16))) float f32x16;

__device__ __forceinline__ float lrelu(float v) { return v >= 0.f ? v : NEG * v; }
__device__ __forceinline__ unsigned short f2bf(float f) {
    unsigned int u = __float_as_uint(f);
    u = (u + 0x7fffu + ((u >> 16) & 1u)) >> 16;
    return (unsigned short)u;
}
__device__ __forceinline__ unsigned int pk2(float a, float b) {
    __hip_bfloat162 h = __float22bfloat162_rn(float2{a, b});
    return *(unsigned int*)&h;
}
__device__ __forceinline__ float2 upk(unsigned int u) {
    return float2{__uint_as_float(u << 16), __uint_as_float(u & 0xffff0000u)};
}
__device__ __forceinline__ f32x2 upkv(unsigned int u) {
    f32x2 r;
    r.x = __uint_as_float(u << 16);
    r.y = __uint_as_float(u & 0xffff0000u);
    return r;
}

// ---------------------------------------------------------------------------
// Weight repack fp32 [M][Cin][3][3] -> bf16 fragment-contiguous layouts.
// mode 0 (16x16x32 fragments): [g][st(3)][mt(M/16)][lane][8]
//   elem = W[mt*16+l15][g*8+cl][tap], tap = st*4+quad (taps>8 zero).
// mode 1 (32x32x16 fragments): [g][ki(5)][mt(M/32)][lane][8]
//   elem = W[mt*32+(lane&31)][g*8+cl][tap], tap = ki*2+(lane>>5) (tap>8 zero).
// ---------------------------------------------------------------------------
struct WSeg { const float* s; unsigned short* d; int K9; int NMT; int validM; int n; int mode; };
struct WArgs { WSeg seg[9]; };

__global__ void wrepack_kernel(WArgs a)
{
    const WSeg sg = a.seg[blockIdx.y];
    int i = blockIdx.x * 256 + threadIdx.x;
    if (i >= sg.n) return;
    int cl = i & 7, lane = (i >> 3) & 63;
    int rest = i >> 9;
    unsigned short v = 0;
    if (sg.mode == 0) {
        int mt = rest % sg.NMT, gs = rest / sg.NMT;
        int st = gs % 3, g = gs / 3;
        int quad = lane >> 4, l15 = lane & 15;
        int co = mt * 16 + l15, tap = st * 4 + quad;
        if (tap < 9 && co < sg.validM)
            v = f2bf(sg.s[(size_t)co * sg.K9 + (g * 8 + cl) * 9 + tap]);
    } else {
        int mt = rest % sg.NMT, kig = rest / sg.NMT;
        int ki = kig % 5, g = kig / 5;
        int hi = lane >> 5, l31 = lane & 31;
        int co = mt * 32 + l31, tap = ki * 2 + hi;
        if (tap < 9 && co < sg.validM)
            v = f2bf(sg.s[(size_t)co * sg.K9 + (g * 8 + cl) * 9 + tap]);
    }
    sg.d[i] = v;
}

// ---------------------------------------------------------------------------
// Fused plain conv (N=64 tile, 2x32), single barrier per group, A-prefetch.
// [r5 form — measured best] Balanced staging: wave wv stages row wv.
// ---------------------------------------------------------------------------
template <int MTW, int SRCF>
__global__ __launch_bounds__(256, 4) void fused_conv(
    const void* __restrict__ actv, const unsigned short* __restrict__ wpad,
    const float* __restrict__ bias, unsigned short* __restrict__ outb,
    float* __restrict__ outf, int Cin, int Cout, int mode)
{
    constexpr int PB = 136 * 16;                 // 2176 B per patch buffer
    constexpr int SMB = 64 * 136 * 2;            // Es (17408) > 2*PB
    __shared__ char smem[SMB];
    unsigned short* Es = (unsigned short*)smem;

    const int t = threadIdx.x;
    const int tile = blockIdx.x, b = blockIdx.z;
    const int lane = t & 63, wv = t >> 6, quad = lane >> 4, l15 = lane & 15;
    const int y0 = (tile >> 2) * 2, x0 = (tile & 3) * 32;
    const int ngrp = Cin >> 3;
    const int NSTR = (Cout >> 4) * 512;          // shorts per (g,st) slab

    const bool sok = lane < 34;
    const int gy = y0 - 1 + wv, gx = x0 - 1 + lane;
    const bool pok = sok && gy >= 0 && gy < HW && gx >= 0 && gx < HW;
    const int gp = pok ? gy * HW + gx : 0;
    const int slot = wv * 34 + lane;

    const float* actf = (const float*)actv;
    const unsigned short* acth = (const unsigned short*)actv;
    const size_t bofs = (size_t)b * Cin * HW2;

    int baddr[3][4];
#pragma unroll
    for (int st = 0; st < 3; ++st) {
        int tap = st * 4 + quad; tap = tap > 8 ? 8 : tap;
        int ky = (tap * 11) >> 5, kx = tap - 3 * ky;
#pragma unroll
        for (int nt = 0; nt < 4; ++nt) {
            int p = nt * 16 + l15, ly = p >> 5, lx = p & 31;
            baddr[st][nt] = ((ly + ky) * 34 + lx + kx) * 16;
        }
    }
    size_t abase[MTW];
#pragma unroll
    for (int m = 0; m < MTW; ++m)
        abase[m] = (size_t)((wv * MTW + m) * 512 + lane * 8);

    f32x4 acc[MTW][4];
#pragma unroll
    for (int m = 0; m < MTW; ++m)
#pragma unroll
        for (int nt = 0; nt < 4; ++nt) acc[m][nt] = (f32x4)(0.f);

    auto load_grp = [&](int g) -> uint4 {
        uint4 u; u.x = u.y = u.z = u.w = 0;
        if (!pok) return u;
        if (SRCF == 1) {
            u = *(const uint4*)(acth + bofs + ((size_t)g * HW2 + gp) * 8);
        } else {
            const float* pl = actf + bofs + (size_t)(g * 8) * HW2 + gp;
            float v0 = pl[0], v1 = pl[HW2], v2 = pl[2 * HW2], v3 = pl[3 * HW2];
            float v4 = pl[4 * HW2], v5 = pl[5 * HW2], v6 = pl[6 * HW2], v7 = pl[7 * HW2];
            u.x = pk2(v0, v1); u.y = pk2(v2, v3);
            u.z = pk2(v4, v5); u.w = pk2(v6, v7);
        }
        return u;
    };

    short8 apre[MTW][3];
    auto loadA = [&](int g) {
#pragma unroll
        for (int st = 0; st < 3; ++st)
#pragma unroll
            for (int m = 0; m < MTW; ++m)
                apre[m][st] = *(const short8*)(wpad + (size_t)(g * 3 + st) * NSTR + abase[m]);
    };

    uint4 cur = load_grp(0);
    if (sok) *(uint4*)(smem + slot * 16) = cur;           // patch buf 0
    loadA(0);
    if (ngrp > 1) cur = load_grp(1);
    __syncthreads();

    for (int g = 0; g < ngrp; ++g) {
        char* pb = smem + (g & 1) * PB;
#pragma unroll
        for (int st = 0; st < 3; ++st) {
            short8 bfr[4];
#pragma unroll
            for (int nt = 0; nt < 4; ++nt)
                bfr[nt] = *(const short8*)(pb + baddr[st][nt]);
#pragma unroll
            for (int m = 0; m < MTW; ++m) {
                short8 a = apre[m][st];
#pragma unroll
                for (int nt = 0; nt < 4; ++nt)
                    acc[m][nt] = __builtin_amdgcn_mfma_f32_16x16x32_bf16(
                        a, bfr[nt], acc[m][nt], 0, 0, 0);
            }
        }
        if (g + 1 < ngrp) {
            if (sok) *(uint4*)(smem + ((g + 1) & 1) * PB + slot * 16) = cur;
            loadA(g + 1);
            if (g + 2 < ngrp) cur = load_grp(g + 2);
        }
        __syncthreads();
    }

    if (mode == 0) {
        constexpr int ESTR = 136;
#pragma unroll
        for (int m = 0; m < MTW; ++m) {
            int cb = (wv * MTW + m) * 16;
#pragma unroll
            for (int nt = 0; nt < 4; ++nt) {
                int px = nt * 16 + l15;
                int co = cb + quad * 4;
                unsigned int u0 = pk2(lrelu(acc[m][nt][0] + bias[co]),
                                      lrelu(acc[m][nt][1] + bias[co + 1]));
                unsigned int u1 = pk2(lrelu(acc[m][nt][2] + bias[co + 2]),
                                      lrelu(acc[m][nt][3] + bias[co + 3]));
                uint2 u; u.x = u0; u.y = u1;
                *(uint2*)&Es[px * ESTR + co] = u;
            }
        }
        __syncthreads();
        const int ng8 = Cout >> 3;
        unsigned short* ob = outb + (size_t)b * Cout * HW2;
        for (int tt = t; tt < 64 * ng8; tt += 256) {
            int cg = tt >> 6, px = tt & 63;
            int gp2 = (y0 + (px >> 5)) * HW + x0 + (px & 31);
            *(uint4*)(ob + ((size_t)cg * HW2 + gp2) * 8) =
                *(const uint4*)&Es[px * ESTR + cg * 8];
        }
    } else {
        float* of = outf + (size_t)b * 18 * HW2;
#pragma unroll
        for (int m = 0; m < MTW; ++m) {
            int cb = (wv * MTW + m) * 16;
#pragma unroll
            for (int nt = 0; nt < 4; ++nt) {
                int px = nt * 16 + l15;
                int gp2 = (y0 + (px >> 5)) * HW + x0 + (px & 31);
#pragma unroll
                for (int r = 0; r < 4; ++r) {
                    int co = cb + quad * 4 + r;
                    if (co < 18)
                        of[(size_t)co * HW2 + gp2] = acc[m][nt][r] + bias[co];
                }
            }
        }
    }
}

// ---------------------------------------------------------------------------
// Fused deformable conv WITH in-kernel offset prediction (phase A).
// Phase A: r5 form (pipelined 4x34 LDS patch) -> offbuf [64][20] f32.
// Loop B: r5 schedule, GEMM = mfma_f32_32x32x16_bf16 (K=80, 5 K-instr).
// Wave mapping (r12): NT=2 (Cout=128): wave wv owns m-tile wv x BOTH n-halves
//   -> A-loads disjoint across waves (5/round), B-reads 10.
// NT=1 (Cout=64): wave wv -> (m = wv>>1, n = wv&1), A 5, B 5.
// mode 0: NHWC8 bf16 out + leaky; mode 1: planar fp32 out + leaky.
// ---------------------------------------------------------------------------
template <int NMT, int NT>
__global__ __launch_bounds__(256, 4) void fused_deform(
    const unsigned short* __restrict__ acth,
    const unsigned short* __restrict__ woff, const float* __restrict__ obias,
    const unsigned short* __restrict__ wpad, const float* __restrict__ bias,
    unsigned short* __restrict__ outb, float* __restrict__ outf,
    int Cin, int Cout, int mode)
{
    constexpr int PATW = 43, PATR = 8, PATP = PATR * PATW;  // 344
    constexpr int CSTR = 88;
    constexpr int PB = PATP * 16;                 // 5504 B
    constexpr int CB = 64 * CSTR * 2;             // 11264 B
    constexpr int SMB = 2 * PB + 2 * CB;          // 33536 B
    constexpr int OPB = 136 * 16;                 // 2176 B small patch (phase A)
    __shared__ char smem[SMB];
    unsigned short* Es = (unsigned short*)smem;   // epilogue alias (17408 B)

    const int t = threadIdx.x;
    const int tile = blockIdx.x, b = blockIdx.z;
    const int lane = t & 63, wv = t >> 6, quad = lane >> 4, l15 = lane & 15;
    const int l31 = lane & 31, hi = lane >> 5;
    const int y0 = (tile >> 2) * 2, x0 = (tile & 3) * 32;
    const int ngrp = Cin >> 3;
    const int NSTR2 = NMT * 512;                  // shorts per (g,ki) slab
    const int py0 = y0 - 3, px0 = x0 - 5;
    const size_t bofs = (size_t)b * Cin * HW2;

    // zero Cs k-pad [72,80) in BOTH buffers: 2 bufs x 64 rows x 1 uint4 = 128
    for (int i = t; i < 128; i += 256) {
        int bu = i >> 6, p = i & 63;
        uint4 z; z.x = z.y = z.z = z.w = 0;
        *(uint4*)(smem + 2 * PB + bu * CB + (p * CSTR + 72) * 2) = z;
    }

    // ---- phase A: offset conv (18ch) -> offbuf [64][20] f32 @ [4352,9472) ----
    {
        float* offbuf = (float*)(smem + 2 * OPB);
        const bool asok = lane < 34;
        const int agy = y0 - 1 + wv, agx = x0 - 1 + lane;
        const bool apok = asok && agy >= 0 && agy < HW && agx >= 0 && agx < HW;
        const int agp = apok ? agy * HW + agx : 0;
        const int aslot = wv * 34 + lane;

        const int mtile = wv & 1, npair = wv >> 1;
        int obad[3][2];
#pragma unroll
        for (int st = 0; st < 3; ++st) {
            int tap = st * 4 + quad; tap = tap > 8 ? 8 : tap;
            int ky = (tap * 11) >> 5, kx = tap - 3 * ky;
#pragma unroll
            for (int nn = 0; nn < 2; ++nn) {
                int p = (2 * npair + nn) * 16 + l15, ly = p >> 5, lx = p & 31;
                obad[st][nn] = ((ly + ky) * 34 + lx + kx) * 16;
            }
        }
        const size_t oa0 = (size_t)(mtile * 512 + lane * 8);

        f32x4 oacc[2];
        oacc[0] = (f32x4)(0.f); oacc[1] = (f32x4)(0.f);
        short8 oapre[3];
        auto loadAO = [&](int g) {
#pragma unroll
            for (int st = 0; st < 3; ++st)
                oapre[st] = *(const short8*)(woff + (size_t)(g * 3 + st) * 1024 + oa0);
        };
        auto load_g = [&](int g) -> uint4 {
            uint4 u; u.x = u.y = u.z = u.w = 0;
            if (apok) u = *(const uint4*)(acth + bofs + ((size_t)g * HW2 + agp) * 8);
            return u;
        };

        uint4 cur = load_g(0);
        if (asok) *(uint4*)(smem + aslot * 16) = cur;
        loadAO(0);
        if (ngrp > 1) cur = load_g(1);
        __syncthreads();

        for (int g = 0; g < ngrp; ++g) {
            const char* pb = smem + (g & 1) * OPB;
#pragma unroll
            for (int st = 0; st < 3; ++st) {
                short8 a = oapre[st];
#pragma unroll
                for (int nn = 0; nn < 2; ++nn) {
                    short8 bf = *(const short8*)(pb + obad[st][nn]);
                    oacc[nn] = __builtin_amdgcn_mfma_f32_16x16x32_bf16(
                        a, bf, oacc[nn], 0, 0, 0);
                }
            }
            if (g + 1 < ngrp) {
                if (asok) *(uint4*)(smem + ((g + 1) & 1) * OPB + aslot * 16) = cur;
                loadAO(g + 1);
                if (g + 2 < ngrp) cur = load_g(g + 2);
            }
            __syncthreads();
        }

        {
            int co0 = mtile * 16 + quad * 4;
            if (co0 < 18) {
#pragma unroll
                for (int nn = 0; nn < 2; ++nn) {
                    int px = (2 * npair + nn) * 16 + l15;
#pragma unroll
                    for (int r = 0; r < 4; ++r)
                        if (co0 + r < 18)
                            offbuf[px * 20 + co0 + r] = oacc[nn][r] + obias[co0 + r];
                }
            }
        }
        __syncthreads();
    }
    const float* offbuf = (const float*)(smem + 2 * OPB);

    // ---- phase 0: fast-path tap params (slots t, t+256, t+512) ----
    float w00[3], w01[3], w10[3], w11[3];
    int pbase[3], csad[3], svalid[3];
    int allin = 1;
    {
#pragma unroll
        for (int s = 0; s < 3; ++s) {
            int task = t + s * 256;
            svalid[s] = task < 576;
            int task2 = svalid[s] ? task : 0;
            int p = task2 / 9, k = task2 - 9 * p;
            int yy = y0 + (p >> 5), xx = x0 + (p & 31);
            float2 dd = *(const float2*)(offbuf + p * 20 + 2 * k);
            float dy = dd.x, dx = dd.y;
            float py = (float)(yy + k / 3 - 1) + dy;
            float px = (float)(xx + k % 3 - 1) + dx;
            float fy = floorf(py), fx = floorf(px);
            float wy = py - fy, wx = px - fx;
            int iy = (int)fy, ix = (int)fx;
            w00[s] = (1.f - wy) * (1.f - wx);
            w01[s] = (1.f - wy) * wx;
            w10[s] = wy * (1.f - wx);
            w11[s] = wy * wx;
            pbase[s] = ((iy - py0) * PATW + (ix - px0)) * 16;   // bytes
            csad[s] = (p * CSTR + k * 8) * 2;                   // bytes
            bool ip = iy >= py0 && iy + 1 <= py0 + (PATR - 1)
                   && ix >= px0 && ix + 1 <= px0 + (PATW - 1);
            if (!ip) allin = 0;
        }
    }
    const int fast = __syncthreads_and(allin);

    // balanced staging: wave wv owns slots [wv*86, wv*86+86)
    const int s0 = wv * 86 + lane;                 // always < 344
    const int r0 = s0 / PATW, c0_ = s0 - PATW * r0;
    const int gy0_ = py0 + r0, gx0_ = px0 + c0_;
    const bool ok0 = gy0_ >= 0 && gy0_ < HW && gx0_ >= 0 && gx0_ < HW;
    const int go0 = ok0 ? gy0_ * HW + gx0_ : 0;
    const bool has1 = lane < 22;
    const int s1 = wv * 86 + 64 + lane;            // < 344 when has1
    const int r1 = s1 / PATW, c1_ = s1 - PATW * r1;
    const int gy1_ = py0 + r1, gx1_ = px0 + c1_;
    const bool ok1 = has1 && gy1_ >= 0 && gy1_ < HW && gx1_ >= 0 && gx1_ < HW;
    const int go1 = ok1 ? gy1_ * HW + gx1_ : 0;

    // 32x32x16 tiling: NT=2 -> m-tile = wv, n in {0,1}; NT=1 -> (wv>>1, wv&1)
    const int mt0 = (NT == 2) ? wv : (wv >> 1);
    const size_t abase2 = (size_t)(mt0 * 512 + lane * 8);
    int bbn[NT];
#pragma unroll
    for (int n = 0; n < NT; ++n) {
        int nh = (NT == 2) ? n : (wv & 1);
        bbn[n] = (nh * 32 + l31) * (CSTR * 2) + hi * 16;
    }

    f32x16 acc2[NT];
#pragma unroll
    for (int n = 0; n < NT; ++n) acc2[n] = (f32x16)(0.f);

    short8 apre[5];
    auto loadA = [&](int g) {
#pragma unroll
        for (int ki = 0; ki < 5; ++ki)
            apre[ki] = *(const short8*)(
                wpad + (size_t)(g * 5 + ki) * NSTR2 + abase2);
    };

    auto mfma32 = [&](const char* cs) {
#pragma unroll
        for (int ki = 0; ki < 5; ++ki) {
            short8 bf[NT];
#pragma unroll
            for (int n = 0; n < NT; ++n)
                bf[n] = *(const short8*)(cs + bbn[n] + ki * 32);
#pragma unroll
            for (int n = 0; n < NT; ++n)
                acc2[n] = __builtin_amdgcn_mfma_f32_32x32x16_bf16(
                    apre[ki], bf[n], acc2[n], 0, 0, 0);
        }
    };

    if (fast) {
        uint4 u0, u1;
        u0.x = u0.y = u0.z = u0.w = 0; u1 = u0;
        if (ok0) u0 = *(const uint4*)(acth + bofs + (size_t)go0 * 8);
        if (ok1) u1 = *(const uint4*)(acth + bofs + (size_t)go1 * 8);
        *(uint4*)(smem + s0 * 16) = u0;
        if (has1) *(uint4*)(smem + s1 * 16) = u1;
        if (ngrp > 1) {
            u0.x = u0.y = u0.z = u0.w = 0; u1 = u0;
            if (ok0) u0 = *(const uint4*)(acth + bofs + ((size_t)HW2 + go0) * 8);
            if (ok1) u1 = *(const uint4*)(acth + bofs + ((size_t)HW2 + go1) * 8);
        }
        __syncthreads();

        for (int g = 0; g < ngrp; ++g) {
            const char* pb = smem + (g & 1) * PB;
            char* csW = smem + 2 * PB + (g & 1) * CB;

            // (a) MFMA for previous group (A already in regs)
            if (g > 0)
                mfma32(smem + 2 * PB + ((g - 1) & 1) * CB);

            // (b) col build g -> Cs[g&1] (packed f32x2 math)
#pragma unroll
            for (int s = 0; s < 3; ++s) {
                if (!svalid[s]) continue;
                const char* base = pb + pbase[s];
                uint4 c00 = *(const uint4*)base;
                uint4 c01 = *(const uint4*)(base + 16);
                uint4 c10 = *(const uint4*)(base + PATW * 16);
                uint4 c11 = *(const uint4*)(base + PATW * 16 + 16);
                f32x2 vw0 = (f32x2)(w00[s]), vw1 = (f32x2)(w01[s]);
                f32x2 vw2 = (f32x2)(w10[s]), vw3 = (f32x2)(w11[s]);
                f32x2 a0 = vw0 * upkv(c00.x) + vw1 * upkv(c01.x)
                         + vw2 * upkv(c10.x) + vw3 * upkv(c11.x);
                f32x2 a1 = vw0 * upkv(c00.y) + vw1 * upkv(c01.y)
                         + vw2 * upkv(c10.y) + vw3 * upkv(c11.y);
                f32x2 a2 = vw0 * upkv(c00.z) + vw1 * upkv(c01.z)
                         + vw2 * upkv(c10.z) + vw3 * upkv(c11.z);
                f32x2 a3 = vw0 * upkv(c00.w) + vw1 * upkv(c01.w)
                         + vw2 * upkv(c10.w) + vw3 * upkv(c11.w);
                uint4 ou;
                ou.x = pk2(a0.x, a0.y); ou.y = pk2(a1.x, a1.y);
                ou.z = pk2(a2.x, a2.y); ou.w = pk2(a3.x, a3.y);
                *(uint4*)(csW + csad[s]) = ou;
            }

            // (c) write patch g+1; (d) prefetch A(g); (e) load act g+2
            if (g + 1 < ngrp) {
                char* pn = smem + ((g + 1) & 1) * PB;
                *(uint4*)(pn + s0 * 16) = u0;
                if (has1) *(uint4*)(pn + s1 * 16) = u1;
            }
            loadA(g);
            if (g + 2 < ngrp) {
                u0.x = u0.y = u0.z = u0.w = 0; u1 = u0;
                if (ok0) u0 = *(const uint4*)(acth + bofs +
                                              ((size_t)(g + 2) * HW2 + go0) * 8);
                if (ok1) u1 = *(const uint4*)(acth + bofs +
                                              ((size_t)(g + 2) * HW2 + go1) * 8);
            }
            __syncthreads();
        }
        // final group's MFMA (apre = A(ngrp-1))
        mfma32(smem + 2 * PB + ((ngrp - 1) & 1) * CB);
    } else {
        // slow path (rare): recompute taps per group from offbuf; global
        // corner reads; 2 barriers per group; single Cs buffer (buffer 0).
        char* csW = smem + 2 * PB;
        for (int g = 0; g < ngrp; ++g) {
            const unsigned short* gb = acth + bofs + (size_t)g * HW2 * 8;
#pragma unroll
            for (int s = 0; s < 3; ++s) {
                if (!svalid[s]) continue;
                int task = t + s * 256;
                int p = task / 9, k = task - 9 * p;
                int yy = y0 + (p >> 5), xx = x0 + (p & 31);
                float2 dd = *(const float2*)(offbuf + p * 20 + 2 * k);
                float dy = dd.x, dx = dd.y;
                float py = (float)(yy + k / 3 - 1) + dy;
                float px = (float)(xx + k % 3 - 1) + dx;
                float fy = floorf(py), fx = floorf(px);
                float wy = py - fy, wx = px - fx;
                int iy = (int)fy, ix = (int)fx;
                float f0 = 0, f1 = 0, f2 = 0, f3 = 0, f4 = 0, f5 = 0, f6 = 0, f7 = 0;
#pragma unroll
                for (int q = 0; q < 4; ++q) {
                    int ddy = q >> 1, ddx = q & 1;
                    int sy = iy + ddy, sx = ix + ddx;
                    float w = (ddy ? wy : 1.f - wy) * (ddx ? wx : 1.f - wx);
                    if (sy < 0 || sy >= HW || sx < 0 || sx >= HW) w = 0.f;
                    int cy = min(max(sy, 0), HW - 1), cx = min(max(sx, 0), HW - 1);
                    uint4 c = *(const uint4*)(gb + (size_t)(cy * HW + cx) * 8);
                    float2 p0 = upk(c.x), p1 = upk(c.y), p2 = upk(c.z), p3 = upk(c.w);
                    f0 += w * p0.x; f1 += w * p0.y; f2 += w * p1.x; f3 += w * p1.y;
                    f4 += w * p2.x; f5 += w * p2.y; f6 += w * p3.x; f7 += w * p3.y;
                }
                uint4 ou;
                ou.x = pk2(f0, f1); ou.y = pk2(f2, f3);
                ou.z = pk2(f4, f5); ou.w = pk2(f6, f7);
                *(uint4*)(csW + csad[s]) = ou;
            }
            __syncthreads();
            loadA(g);
            mfma32(csW);
            __syncthreads();
        }
    }

    // ---- epilogue (32x32 C/D layout: col=lane&31,
    //      row = (reg&3) + 8*(reg>>2) + 4*(lane>>5)) ----
    __syncthreads();   // Es aliases patch/Cs regions
    if (mode == 0) {
        constexpr int ESTR = 136;
        int mtb = mt0 * 32;
#pragma unroll
        for (int n = 0; n < NT; ++n) {
            int px2 = ((NT == 2) ? n : (wv & 1)) * 32 + l31;
#pragma unroll
            for (int q = 0; q < 4; ++q) {
                int co = mtb + q * 8 + hi * 4;
                unsigned int u0 = pk2(lrelu(acc2[n][q * 4 + 0] + bias[co]),
                                      lrelu(acc2[n][q * 4 + 1] + bias[co + 1]));
                unsigned int u1 = pk2(lrelu(acc2[n][q * 4 + 2] + bias[co + 2]),
                                      lrelu(acc2[n][q * 4 + 3] + bias[co + 3]));
                uint2 u; u.x = u0; u.y = u1;
                *(uint2*)&Es[px2 * ESTR + co] = u;
            }
        }
        __syncthreads();
        const int ng8 = Cout >> 3;
        unsigned short* ob = outb + (size_t)b * Cout * HW2;
        for (int tt = t; tt < 64 * ng8; tt += 256) {
            int cg = tt >> 6, px = tt & 63;
            int gp2 = (y0 + (px >> 5)) * HW + x0 + (px & 31);
            *(uint4*)(ob + ((size_t)cg * HW2 + gp2) * 8) =
                *(const uint4*)&Es[px * ESTR + cg * 8];
        }
    } else {
        float* of = outf + (size_t)b * Cout * HW2;
        int mtb = mt0 * 32;
#pragma unroll
        for (int n = 0; n < NT; ++n) {
            int px2 = ((NT == 2) ? n : (wv & 1)) * 32 + l31;
            int gp2 = (y0 + (px2 >> 5)) * HW + x0 + (px2 & 31);
#pragma unroll
            for (int q = 0; q < 4; ++q) {
                int co = mtb + q * 8 + hi * 4;
#pragma unroll
                for (int rr = 0; rr < 4; ++rr)
                    of[(size_t)(co + rr) * HW2 + gp2] =
                        lrelu(acc2[n][q * 4 + rr] + bias[co + rr]);
            }
        }
    }
}

// ---------------------------------------------------------------------------
extern "C" void kernel_launch(void* const* d_in, const int* in_sizes, int n_in,
                              void* d_out, int out_size, void* d_ws,
                              size_t ws_size, hipStream_t stream)
{
    const float* x = (const float*)d_in[0];
    const float* p[18];
    for (int i = 0; i < 18; ++i) p[i] = (const float*)d_in[1 + i];

    char* ws = (char*)d_ws;
    unsigned short* A1 = (unsigned short*)ws;              // NHWC8 bf16
    unsigned short* A2 = (unsigned short*)(ws + 16777216);
    unsigned short* WB = (unsigned short*)(ws + 38273024);

    unsigned short* Wc1 = WB;             // mode0: 8g x3 x8mt x512
    unsigned short* Wo1 = Wc1 + 98304;    // mode0: 16g x3 x2mt x512
    unsigned short* Wd1 = Wo1 + 49152;    // mode1: 16g x5 x4mt x512
    unsigned short* Wc2 = Wd1 + 163840;   // mode0: 16g x3 x8mt x512
    unsigned short* Wo2 = Wc2 + 196608;   // mode0: 16g x3 x2mt x512
    unsigned short* Wd2 = Wo2 + 49152;    // mode1: 16g x5 x4mt x512
    unsigned short* Wc3 = Wd2 + 163840;   // mode0: 16g x3 x4mt x512
    unsigned short* Wo3 = Wc3 + 98304;    // mode0: 8g x3 x2mt x512
    unsigned short* Wd3 = Wo3 + 24576;    // mode1: 8g x5 x2mt x512

    WArgs wa;
    wa.seg[0] = {p[0],  Wc1,  576, 8, 128,  98304, 0};
    wa.seg[1] = {p[2],  Wo1, 1152, 2,  18,  49152, 0};
    wa.seg[2] = {p[4],  Wd1, 1152, 4, 128, 163840, 1};
    wa.seg[3] = {p[6],  Wc2, 1152, 8, 128, 196608, 0};
    wa.seg[4] = {p[8],  Wo2, 1152, 2,  18,  49152, 0};
    wa.seg[5] = {p[10], Wd2, 1152, 4, 128, 163840, 1};
    wa.seg[6] = {p[12], Wc3, 1152, 4,  64,  98304, 0};
    wa.seg[7] = {p[14], Wo3,  576, 2,  18,  24576, 0};
    wa.seg[8] = {p[16], Wd3,  576, 2,  64,  40960, 1};
    wrepack_kernel<<<dim3(768, 9), 256, 0, stream>>>(wa);

    dim3 g(256, 1, 4);      // 2x32 tiles
    // stage 1: conv (fp32 planar in, staged) -> deform(fused offset conv)
    fused_conv<2, 0><<<g, 256, 0, stream>>>(x, Wc1, p[1], A1, nullptr, 64, 128, 0);
    fused_deform<4, 2><<<g, 256, 0, stream>>>(A1, Wo1, p[3], Wd1, p[5], A2, nullptr, 128, 128, 0);
    // stage 2
    fused_conv<2, 1><<<g, 256, 0, stream>>>(A2, Wc2, p[7], A1, nullptr, 128, 128, 0);
    fused_deform<4, 2><<<g, 256, 0, stream>>>(A1, Wo2, p[9], Wd2, p[11], A2, nullptr, 128, 128, 0);
    // stage 3
    fused_conv<1, 1><<<g, 256, 0, stream>>>(A2, Wc3, p[13], A1, nullptr, 128, 64, 0);
    fused_deform<2, 1><<<g, 256, 0, stream>>>(A1, Wo3, p[15], Wd3, p[17], nullptr, (float*)d_out, 64, 64, 1);
}